// Round 9
// baseline (355.888 us; speedup 1.0000x reference)
//
#include <hip/hip_runtime.h>

#define B_ 2
#define S_ 2048
#define E_ 2048
#define H_ 16
#define G_ 4
#define HD_ 128
#define GD_ 512
#define KVLD_ 1024
#define QKVN_ 3072
#define M_ (B_*S_)   // 4096

using u16 = unsigned short;
using u32 = unsigned int;
typedef __attribute__((ext_vector_type(8))) short short8;
typedef __attribute__((ext_vector_type(4))) float f32x4;

// scale * log2(e), folded into Q so scores come out in log2 domain
#define QSCL 0.12751891114f   // (1/sqrt(128)) * 1.4426950408889634
#define MASKED_L2 (-14427.0f) // -10000 * log2(e)

__device__ __forceinline__ u16 f2bf(float f) {
  union { float f; unsigned u; } v; v.f = f;
  unsigned r = v.u + 0x7fff + ((v.u >> 16) & 1);  // RNE
  return (u16)(r >> 16);
}

__device__ __forceinline__ void async16(const void* g, void* l) {
  __builtin_amdgcn_global_load_lds((const __attribute__((address_space(1))) unsigned int*)g,
                                   (__attribute__((address_space(3))) unsigned int*)l, 16, 0, 0);
}

// ---------------- fused: f32->bf16 cast (x) + bias concat ----------------
__global__ __launch_bounds__(256) void cast_plus(const float* __restrict__ in,
                                                 u16* __restrict__ out, int n4,
                                                 const float* __restrict__ ba,
                                                 const float* __restrict__ bbk,
                                                 const float* __restrict__ bc,
                                                 float* __restrict__ bo) {
  if ((int)blockIdx.x >= (n4 + 255) / 256) {   // tail blocks: bias concat
    int t = (blockIdx.x - (n4 + 255) / 256) * 256 + threadIdx.x;
    if (t < 2048) bo[t] = ba[t];
    else if (t < 2560) bo[t] = bbk[t - 2048];
    else if (t < 3072) bo[t] = bc[t - 2560];
    return;
  }
  int i = blockIdx.x * 256 + threadIdx.x;
  if (i >= n4) return;
  float4 v = ((const float4*)in)[i];
  union { u16 o[4]; uint2 u; } pk;
  pk.o[0] = f2bf(v.x); pk.o[1] = f2bf(v.y); pk.o[2] = f2bf(v.z); pk.o[3] = f2bf(v.w);
  *(uint2*)(out + (size_t)i * 4) = pk.u;
}

// ------------- fused W transpose-cast: all 4 weights in one launch -------------
__global__ __launch_bounds__(256) void transpose_cast4(const float* __restrict__ Wq,
                                                       const float* __restrict__ Wk,
                                                       const float* __restrict__ Wv,
                                                       const float* __restrict__ Wo,
                                                       u16* __restrict__ Wqkvt,
                                                       u16* __restrict__ Wot) {
  __shared__ u16 tile[64 * 72];
  int b = blockIdx.x;
  const float* W; u16* Wt; int N, bx;
  if (b < 1024)      { W = Wq; Wt = Wqkvt;                     N = E_;  bx = b;        }
  else if (b < 1280) { W = Wk; Wt = Wqkvt + (size_t)2048 * E_; N = GD_; bx = b - 1024; }
  else if (b < 1536) { W = Wv; Wt = Wqkvt + (size_t)2560 * E_; N = GD_; bx = b - 1280; }
  else               { W = Wo; Wt = Wot;                       N = E_;  bx = b - 1536; }
  int nbx = N / 64;
  int n0 = (bx % nbx) * 64, k0 = (bx / nbx) * 64;
  int t = threadIdx.x;
  int row = t >> 2;       // k_local 0..63
  int seg = t & 3;        // 16 f32 each
  const float* src = W + (size_t)(k0 + row) * N + n0 + seg * 16;
  #pragma unroll
  for (int i = 0; i < 4; ++i) {
    float4 v = *(const float4*)(src + i * 4);
    int nl = seg * 16 + i * 4;
    tile[(nl + 0) * 72 + row] = f2bf(v.x);
    tile[(nl + 1) * 72 + row] = f2bf(v.y);
    tile[(nl + 2) * 72 + row] = f2bf(v.z);
    tile[(nl + 3) * 72 + row] = f2bf(v.w);
  }
  __syncthreads();
  int nl = t >> 2, s2 = t & 3;   // 16 bf16 per thread
  u16* dst = Wt + (size_t)(n0 + nl) * E_ + k0 + s2 * 16;
  *(uint4*)dst       = *(const uint4*)&tile[nl * 72 + s2 * 16];
  *(uint4*)(dst + 8) = *(const uint4*)&tile[nl * 72 + s2 * 16 + 8];
}

// ------------- V (from KVb, cols 512..1023) -> Vtg[(bb*G+g)*HD+n][S] with
// kv permuted within each 32-block: phys = (kv&15)*2 + (kv>>4)  (matches the
// P u32 pack: pair (kv=c, kv=c+16) -> phys {2c, 2c+1}). [R7-verified] -------------
__global__ __launch_bounds__(256) void transpose_v(const u16* __restrict__ KVb, u16* __restrict__ Vtg) {
  __shared__ u16 tile[64 * 72];
  int kv0 = blockIdx.x * 64;      // over M_
  int gn0 = blockIdx.y * 64;      // over GD_
  int t = threadIdx.x;
  int row = t >> 2, seg = t & 3;
  int r32 = row & 31;
  int prow = (row & 32) + (r32 & 15) * 2 + (r32 >> 4);   // per-32-block kv permutation
  const u16* src = KVb + (size_t)(kv0 + row) * KVLD_ + 512 + gn0 + seg * 16;
  union { uint4 v; u16 s[8]; } a, b;
  a.v = *(const uint4*)src; b.v = *(const uint4*)(src + 8);
  #pragma unroll
  for (int j = 0; j < 8; ++j) tile[(seg * 16 + j) * 72 + prow] = a.s[j];
  #pragma unroll
  for (int j = 0; j < 8; ++j) tile[(seg * 16 + 8 + j) * 72 + prow] = b.s[j];
  __syncthreads();
  int gl = t >> 2, ks2 = t & 3;
  int bb = kv0 >> 11;
  int s0 = kv0 & 2047;
  int gn = gn0 + gl;
  u16* dst = Vtg + (size_t)(bb * 512 + gn) * S_ + s0 + ks2 * 16;
  *(uint4*)dst       = *(const uint4*)&tile[gl * 72 + ks2 * 16];
  *(uint4*)(dst + 8) = *(const uint4*)&tile[gl * 72 + ks2 * 16 + 8];
}

// ------------- mask all-ones flags per (bb, 16-row group, 64-col tile) -------------
__global__ __launch_bounds__(256) void mask_flags(const int* __restrict__ mask, int* __restrict__ flags) {
  int idx = blockIdx.x * 4 + (threadIdx.x >> 6);
  int lane = threadIdx.x & 63;
  int bb = idx >> 12, rg = (idx >> 5) & 127, kt = idx & 31;
  const int* base = mask + ((size_t)bb * S_ + rg * 16) * S_ + kt * 64;
  int row = lane >> 2, c0 = (lane & 3) * 16;
  int ok = 1;
  #pragma unroll
  for (int i = 0; i < 4; ++i) {
    int4 v = *(const int4*)&base[(size_t)row * S_ + c0 + i * 4];
    ok &= (v.x != 0) & (v.y != 0) & (v.z != 0) & (v.w != 0);
  }
  ok = __all(ok) ? 1 : 0;
  if (lane == 0) flags[idx] = ok;
}

// ------------- fused QKV GEMM: A(MxK) * Wqkvt(3072xK)^T + bias; split epilogue. -------------
__global__ __launch_bounds__(256) void gemm_qkv(const u16* __restrict__ A, const u16* __restrict__ Bt,
                                                const float* __restrict__ bias,
                                                u16* __restrict__ Qb, u16* __restrict__ KVb, int K) {
  __shared__ u16 As[2][128 * 32];
  __shared__ u16 Bs[2][128 * 32];
  int nbx = gridDim.x;
  int bid = blockIdx.y * nbx + blockIdx.x;
  int chunk = (nbx * gridDim.y) >> 3;
  int swz = (bid & 7) * chunk + (bid >> 3);
  int n0 = (swz % nbx) * 128, m0 = (swz / nbx) * 128;
  int t = threadIdx.x;
  int w = t >> 6, lane = t & 63, c = lane & 15, q = lane >> 4;
  int wm = w & 1, wn = w >> 1;
  int r0 = t >> 2;
  int kcs = ((t & 3) ^ ((t >> 3) & 3)) * 8;    // pre-swizzled source chunk
  const u16* Ag0 = A  + (size_t)(m0 + r0) * K + kcs;
  const u16* Ag1 = A  + (size_t)(m0 + 64 + r0) * K + kcs;
  const u16* Bg0 = Bt + (size_t)(n0 + r0) * K + kcs;
  const u16* Bg1 = Bt + (size_t)(n0 + 64 + r0) * K + kcs;
  int roff = (q ^ ((c >> 1) & 3)) * 8;         // swizzled read chunk
  f32x4 acc[4][4] = {};
  async16(Ag0, &As[0][t * 8]);
  async16(Ag1, &As[0][2048 + t * 8]);
  async16(Bg0, &Bs[0][t * 8]);
  async16(Bg1, &Bs[0][2048 + t * 8]);
  for (int k0 = 0; k0 < K; k0 += 32) {
    int cur = (k0 >> 5) & 1;
    __syncthreads();   // implicit vmcnt(0) drain: buf[cur] staged, buf[cur^1] free
    if (k0 + 32 < K) {
      async16(Ag0 + k0 + 32, &As[cur ^ 1][t * 8]);
      async16(Ag1 + k0 + 32, &As[cur ^ 1][2048 + t * 8]);
      async16(Bg0 + k0 + 32, &Bs[cur ^ 1][t * 8]);
      async16(Bg1 + k0 + 32, &Bs[cur ^ 1][2048 + t * 8]);
    }
    short8 af[4], bf[4];
    #pragma unroll
    for (int i = 0; i < 4; ++i) {
      af[i] = *(const short8*)&As[cur][(wm * 64 + i * 16 + c) * 32 + roff];
      bf[i] = *(const short8*)&Bs[cur][(wn * 64 + i * 16 + c) * 32 + roff];
    }
    #pragma unroll
    for (int i = 0; i < 4; ++i)
      #pragma unroll
      for (int j = 0; j < 4; ++j)
        acc[i][j] = __builtin_amdgcn_mfma_f32_16x16x32_bf16(af[i], bf[j], acc[i][j], 0, 0, 0);
  }
  int isq = (n0 < 2048);           // block-uniform
  #pragma unroll
  for (int i = 0; i < 4; ++i) {
    int mrow_base = m0 + wm * 64 + i * 16 + q * 4;
    #pragma unroll
    for (int j = 0; j < 4; ++j) {
      int coln = n0 + wn * 64 + j * 16 + c;
      float bv = bias[coln];
      #pragma unroll
      for (int r = 0; r < 4; ++r) {
        float v = acc[i][j][r] + bv;
        if (isq) Qb[(size_t)(mrow_base + r) * E_ + coln] = f2bf(v * QSCL);
        else     KVb[(size_t)(mrow_base + r) * KVLD_ + coln - 2048] = f2bf(v);
      }
    }
  }
}

// ------------- O-proj GEMM: C(MxN f32) = A(MxK) * Bt(NxK)^T + bias. -------------
__global__ __launch_bounds__(256) void gemm_k(const u16* __restrict__ A, const u16* __restrict__ Bt,
                                              const float* __restrict__ bias, float* __restrict__ Cout,
                                              int M, int N, int K) {
  __shared__ u16 As[2][128 * 32];
  __shared__ u16 Bs[2][128 * 32];
  int nbx = gridDim.x;
  int bid = blockIdx.y * nbx + blockIdx.x;
  int chunk = (nbx * gridDim.y) >> 3;
  int swz = (bid & 7) * chunk + (bid >> 3);
  int n0 = (swz % nbx) * 128, m0 = (swz / nbx) * 128;
  int t = threadIdx.x;
  int w = t >> 6, lane = t & 63, c = lane & 15, q = lane >> 4;
  int wm = w & 1, wn = w >> 1;
  int r0 = t >> 2;
  int kcs = ((t & 3) ^ ((t >> 3) & 3)) * 8;
  const u16* Ag0 = A  + (size_t)(m0 + r0) * K + kcs;
  const u16* Ag1 = A  + (size_t)(m0 + 64 + r0) * K + kcs;
  const u16* Bg0 = Bt + (size_t)(n0 + r0) * K + kcs;
  const u16* Bg1 = Bt + (size_t)(n0 + 64 + r0) * K + kcs;
  int roff = (q ^ ((c >> 1) & 3)) * 8;
  f32x4 acc[4][4] = {};
  async16(Ag0, &As[0][t * 8]);
  async16(Ag1, &As[0][2048 + t * 8]);
  async16(Bg0, &Bs[0][t * 8]);
  async16(Bg1, &Bs[0][2048 + t * 8]);
  for (int k0 = 0; k0 < K; k0 += 32) {
    int cur = (k0 >> 5) & 1;
    __syncthreads();
    if (k0 + 32 < K) {
      async16(Ag0 + k0 + 32, &As[cur ^ 1][t * 8]);
      async16(Ag1 + k0 + 32, &As[cur ^ 1][2048 + t * 8]);
      async16(Bg0 + k0 + 32, &Bs[cur ^ 1][t * 8]);
      async16(Bg1 + k0 + 32, &Bs[cur ^ 1][2048 + t * 8]);
    }
    short8 af[4], bf[4];
    #pragma unroll
    for (int i = 0; i < 4; ++i) {
      af[i] = *(const short8*)&As[cur][(wm * 64 + i * 16 + c) * 32 + roff];
      bf[i] = *(const short8*)&Bs[cur][(wn * 64 + i * 16 + c) * 32 + roff];
    }
    #pragma unroll
    for (int i = 0; i < 4; ++i)
      #pragma unroll
      for (int j = 0; j < 4; ++j)
        acc[i][j] = __builtin_amdgcn_mfma_f32_16x16x32_bf16(af[i], bf[j], acc[i][j], 0, 0, 0);
  }
  #pragma unroll
  for (int i = 0; i < 4; ++i) {
    int mrow_base = m0 + wm * 64 + i * 16 + q * 4;
    #pragma unroll
    for (int j = 0; j < 4; ++j) {
      int coln = n0 + wn * 64 + j * 16 + c;
      float bv = bias[coln];
      #pragma unroll
      for (int r = 0; r < 4; ++r)
        Cout[(size_t)(mrow_base + r) * N + coln] = acc[i][j][r] + bv;
    }
  }
}

// ------------- flash attention: 128 q-rows/block, 4 waves x 2 strips x 16 rows
//   (32 rows/wave halves per-wave K/V fragment re-reads vs 8x16), kv-tile = 32.
//   K/V dbuf in LDS, 1 barrier/tile. LDS = 16K Ks + 16K Vs + 8K Ps = 40KB
//   -> 4 blocks/CU x 4 waves = 16 waves/CU (4/SIMD): R0's traffic with R2's occupancy. -------------
__global__ __launch_bounds__(256) void attn_k(const u16* __restrict__ Q, const u16* __restrict__ KVb,
                                              const u16* __restrict__ Vtg, const int* __restrict__ mask,
                                              const int* __restrict__ mflags, u16* __restrict__ O) {
  __shared__ u16 Ks[2][32 * 128]; // [kv][hd], phys chunk16 = chunkL ^ (kv&15)
  __shared__ u16 Vs[2][128 * 32]; // [d][kv-phys], phys chunk16 = chunkL ^ ((d>>1)&3)
  __shared__ u16 Ps[8 * 16 * 32]; // per-strip 1KB: [row][kv-phys]; chunk swz ^ ((row>>1)&3)
  int bid = blockIdx.x;
  int mt = bid & 15, h = (bid >> 4) & 15, bb = bid >> 8;
  int g = h & 3;                  // jnp.tile => head h uses group h % G
  int t = threadIdx.x, w = t >> 6, lane = t & 63, c = lane & 15, q = lane >> 4;
  int m0 = mt * 128;

  const u16* Qbase  = Q   + (size_t)(bb * S_ + m0) * E_ + h * HD_;
  const u16* Kbase  = KVb + (size_t)bb * S_ * KVLD_ + g * HD_;
  const u16* Vtbase = Vtg + (size_t)(bb * G_ + g) * HD_ * S_;

  // K staging: 256 threads, 2 rounds of 16 kv-rows; src chunk pre-XORed by row&15
  int krow0 = t >> 4;                          // 0..15
  int kkc   = ((t & 15) ^ krow0) * 8;
  const u16* Kst = Kbase + (size_t)krow0 * KVLD_ + kkc;
  // V staging: 2 rounds of 64 d-rows; src chunk pre-XORed by (d>>1)&3
  int vn0 = t >> 2;                            // 0..63
  int vkc = ((t & 3) ^ ((t >> 3) & 3)) * 8;
  const u16* Vst = Vtbase + (size_t)vn0 * S_ + vkc;

  // P addresses (u16 units, per-strip 512). write: u32 pair (kv=c, kv=c+16), row q*4+r;
  // phys chunk = (c>>2) ^ ((row>>1)&3), within-chunk u32 = c&3.  [R7-verified]
  int pwa[2][4], pra[2];
  #pragma unroll
  for (int s = 0; s < 2; ++s) {
    #pragma unroll
    for (int r = 0; r < 4; ++r) {
      int row = q * 4 + r;
      pwa[s][r] = (w * 2 + s) * 512 + row * 32 + (((c >> 2) ^ ((row >> 1) & 3)) << 3) + ((c & 3) << 1);
    }
    pra[s] = (w * 2 + s) * 512 + c * 32 + ((q ^ ((c >> 1) & 3)) << 3);
  }

  // Q fragments (pre-scaled by QSCL); wave w owns rows [w*32, w*32+32), strips of 16
  short8 aq[2][4];
  #pragma unroll
  for (int s = 0; s < 2; ++s)
    #pragma unroll
    for (int k0 = 0; k0 < 4; ++k0)
      aq[s][k0] = *(const short8*)&Qbase[(size_t)(w * 32 + s * 16 + c) * E_ + k0 * 32 + q * 8];

  const short8 ones = {(short)0x3F80, (short)0x3F80, (short)0x3F80, (short)0x3F80,
                       (short)0x3F80, (short)0x3F80, (short)0x3F80, (short)0x3F80};

  f32x4 Oa[2][8] = {};
  f32x4 lacc[2] = {};

  // prologue: stage tile 0 into buffer 0
  #pragma unroll
  for (int p = 0; p < 2; ++p)
    async16(Kst + (size_t)(p * 16) * KVLD_, &Ks[0][p * 2048 + t * 8]);
  #pragma unroll
  for (int p = 0; p < 2; ++p)
    async16(Vst + (size_t)(p * 64) * S_, &Vs[0][p * 2048 + t * 8]);

  for (int kv0 = 0; kv0 < S_; kv0 += 32) {
    int cur = (kv0 >> 5) & 1;
    // single barrier per tile: drain guarantees buf[cur] staged and buf[cur^1] free
    __syncthreads();
    if (kv0 + 32 < S_) {           // prefetch next tile into the other buffer
      #pragma unroll
      for (int p = 0; p < 2; ++p)
        async16(Kst + (size_t)(kv0 + 32 + p * 16) * KVLD_, &Ks[cur ^ 1][p * 2048 + t * 8]);
      #pragma unroll
      for (int p = 0; p < 2; ++p)
        async16(Vst + (size_t)(p * 64) * S_ + kv0 + 32, &Vs[cur ^ 1][p * 2048 + t * 8]);
    }
    const u16* K_ = Ks[cur];
    const u16* V_ = Vs[cur];

    // QK^T (log2 domain): bk fragments shared across both strips
    f32x4 sc[2][2] = {};
    #pragma unroll
    for (int k0 = 0; k0 < 4; ++k0) {
      int koff = (((k0 * 4 + q) ^ c) * 8);
      short8 bk0 = *(const short8*)&K_[c * 128 + koff];
      short8 bk1 = *(const short8*)&K_[(16 + c) * 128 + koff];
      #pragma unroll
      for (int s = 0; s < 2; ++s) {
        sc[s][0] = __builtin_amdgcn_mfma_f32_16x16x32_bf16(aq[s][k0], bk0, sc[s][0], 0, 0, 0);
        sc[s][1] = __builtin_amdgcn_mfma_f32_16x16x32_bf16(aq[s][k0], bk1, sc[s][1], 0, 0, 0);
      }
    }
    // rare mask path (flag granularity 64 cols covers this 32-tile)
    #pragma unroll
    for (int s = 0; s < 2; ++s) {
      int flag = mflags[bb * 4096 + (mt * 8 + w * 2 + s) * 32 + (kv0 >> 6)];
      if (!flag) {
        #pragma unroll
        for (int r = 0; r < 4; ++r) {
          int qrow = m0 + w * 32 + s * 16 + q * 4 + r;
          const int* mrow = mask + ((size_t)bb * S_ + qrow) * S_ + kv0;
          if (mrow[c] == 0)      sc[s][0][r] = MASKED_L2;
          if (mrow[16 + c] == 0) sc[s][1][r] = MASKED_L2;
        }
      }
    }
    // p = exp2(sc); pack pair (kv=c, kv=c+16) -> one u32 store per row per strip
    #pragma unroll
    for (int s = 0; s < 2; ++s)
      #pragma unroll
      for (int r = 0; r < 4; ++r) {
        u32 u0 = __float_as_uint(__builtin_amdgcn_exp2f(sc[s][0][r])) + 0x8000u;
        u32 u1 = __float_as_uint(__builtin_amdgcn_exp2f(sc[s][1][r])) + 0x8000u;
        *(u32*)&Ps[pwa[s][r]] = __builtin_amdgcn_perm(u1, u0, 0x07060302);
      }
    __asm__ volatile("" ::: "memory");   // Ps wave-private: LDS in-order per wave
    // PV + row-sums: ap per strip (1 b128 each); bv shared across strips
    short8 ap0 = *(const short8*)&Ps[pra[0]];
    short8 ap1 = *(const short8*)&Ps[pra[1]];
    lacc[0] = __builtin_amdgcn_mfma_f32_16x16x32_bf16(ap0, ones, lacc[0], 0, 0, 0);
    lacc[1] = __builtin_amdgcn_mfma_f32_16x16x32_bf16(ap1, ones, lacc[1], 0, 0, 0);
    #pragma unroll
    for (int d = 0; d < 8; ++d) {
      short8 bv = *(const short8*)&V_[(d * 16 + c) * 32 + ((q ^ ((c >> 1) & 3)) * 8)];
      Oa[0][d] = __builtin_amdgcn_mfma_f32_16x16x32_bf16(ap0, bv, Oa[0][d], 0, 0, 0);
      Oa[1][d] = __builtin_amdgcn_mfma_f32_16x16x32_bf16(ap1, bv, Oa[1][d], 0, 0, 0);
    }
  }
  #pragma unroll
  for (int s = 0; s < 2; ++s) {
    float inv[4];
    #pragma unroll
    for (int r = 0; r < 4; ++r) inv[r] = 1.0f / lacc[s][r];
    #pragma unroll
    for (int d = 0; d < 8; ++d)
      #pragma unroll
      for (int r = 0; r < 4; ++r) {
        size_t off = (size_t)(bb * S_ + m0 + w * 32 + s * 16 + q * 4 + r) * E_ + h * HD_ + d * 16 + c;
        O[off] = f2bf(Oa[s][d][r] * inv[r]);
      }
  }
}

extern "C" void kernel_launch(void* const* d_in, const int* in_sizes, int n_in,
                              void* d_out, int out_size, void* d_ws, size_t ws_size,
                              hipStream_t stream) {
  const float* x    = (const float*)d_in[0];
  const int*   mask = (const int*)d_in[1];
  const float* Wq   = (const float*)d_in[2];
  const float* bq   = (const float*)d_in[3];
  const float* Wk   = (const float*)d_in[4];
  const float* bk   = (const float*)d_in[5];
  const float* Wv   = (const float*)d_in[6];
  const float* bv   = (const float*)d_in[7];
  const float* Wo   = (const float*)d_in[8];
  const float* bo   = (const float*)d_in[9];
  float* out = (float*)d_out;

  char* ws = (char*)d_ws;
  u16* xb    = (u16*)ws; ws += (size_t)M_ * E_ * 2;
  u16* Wqkvt = (u16*)ws; ws += (size_t)QKVN_ * E_ * 2;
  u16* Wot   = (u16*)ws; ws += (size_t)E_ * E_ * 2;
  u16* Qb    = (u16*)ws; ws += (size_t)M_ * E_ * 2;
  u16* KVb   = (u16*)ws; ws += (size_t)M_ * KVLD_ * 2;
  u16* Ob    = (u16*)ws; ws += (size_t)M_ * E_ * 2;
  u16* Vtg   = (u16*)ws; ws += (size_t)B_ * G_ * HD_ * S_ * 2;
  int* mfl   = (int*)ws; ws += (size_t)B_ * 128 * 32 * 4;
  float* bqkv = (float*)ws; ws += QKVN_ * 4;

  int n4 = M_ * E_ / 4;
  cast_plus<<<(n4 + 255) / 256 + 12, 256, 0, stream>>>(x, xb, n4, bq, bk, bv, bqkv);
  transpose_cast4<<<2560, 256, 0, stream>>>(Wq, Wk, Wv, Wo, Wqkvt, Wot);
  mask_flags<<<B_ * 128 * 32 / 4, 256, 0, stream>>>(mask, mfl);

  gemm_qkv<<<dim3(QKVN_ / 128, M_ / 128), 256, 0, stream>>>(xb, Wqkvt, bqkv, Qb, KVb, E_);
  transpose_v<<<dim3(M_ / 64, GD_ / 64), 256, 0, stream>>>(KVb, Vtg);

  attn_k<<<B_ * H_ * (S_ / 128), 256, 0, stream>>>(Qb, KVb, Vtg, mask, mfl, Ob);

  gemm_k<<<dim3(E_ / 128, M_ / 128), 256, 0, stream>>>(Ob, Wot, bo, out, M_, E_, E_);
}